// Round 1
// 219.248 us; speedup vs baseline: 1.0631x; 1.0631x over previous
//
#include <hip/hip_runtime.h>

#define NP   8192
#define BB   4
#define DIN  32
#define M0   32
#define M1   32
#define M2   64
#define CAP  80
#define CSTR 81            // candidate row stride (odd -> conflict-free)
#define KWV  16            // waves per knn block
#define SEG  (NP / KWV)    // 512 points per wave

typedef float f32x2 __attribute__((ext_vector_type(2)));

__device__ __forceinline__ float lrelu(float x) { return fmaxf(x, 0.1f * x); }
__device__ __forceinline__ unsigned umin_(unsigned a, unsigned b) { return a < b ? a : b; }
__device__ __forceinline__ unsigned umax_(unsigned a, unsigned b) { return a > b ? a : b; }

// monotonic float->uint key (total order incl. negatives)
__device__ __forceinline__ unsigned fkey(float f) {
    unsigned b = __float_as_uint(f);
    return (b & 0x80000000u) ? ~b : (b | 0x80000000u);
}
__device__ __forceinline__ float funkey(unsigned k) {
    unsigned b = (k & 0x80000000u) ? (k & 0x7fffffffu) : ~k;
    return __uint_as_float(b);
}

// round-to-nearest-even f32 -> bf16 (as uint16 in low bits)
__device__ __forceinline__ unsigned bf16rn(float f) {
    unsigned u = __float_as_uint(f);
    unsigned r = (u >> 16) & 1u;
    return (u + 0x7fffu + r) >> 16;
}

// packed f32 FMA: d = a*b + c per 32-bit half. 2 results/instr -> the only
// path to the 157.3 TF f32 spec (scalar v_fma_f32 caps at 78.6 TF).
// b is the wave-uniform operand -> SGPR pair ("s"): 1 SGPR read/instr, legal.
// IEEE-fused per half: bit-identical to scalar fmaf per element.
__device__ __forceinline__ f32x2 pk_fma(f32x2 a, f32x2 b, f32x2 c) {
    f32x2 d;
    asm("v_pk_fma_f32 %0, %1, %2, %3" : "=v"(d) : "v"(a), "s"(b), "v"(c));
    return d;
}

// max with a DPP-permuted copy: full VALU rate, no DS pipe.
template<int CTRL>
__device__ __forceinline__ float fmax_dpp(float v) {
    int s = __builtin_amdgcn_update_dpp(0, __float_as_int(v), CTRL, 0xf, 0xf, true);
    return fmaxf(v, __int_as_float(s));
}

// ---------------------------------------------------------------------------
// Kernel 1: pack pts4 = (x,y,z,|p|^2), ptsS = (-2x,-2y,-2z,|p|^2) and
// feat = W0[:,3:] @ points stored as bf16 pairs. (unchanged)
// ---------------------------------------------------------------------------
__global__ __launch_bounds__(256) void prep_kernel(
    const float* __restrict__ xyz, const float* __restrict__ points,
    const float* __restrict__ W0, float4* __restrict__ pts4,
    float4* __restrict__ ptsS, unsigned* __restrict__ featb)
{
    const int tid  = threadIdx.x;
    const int w    = __builtin_amdgcn_readfirstlane(tid >> 6);  // 0..3
    const int lane = tid & 63;
    const int t    = blockIdx.x * 64 + lane;     // point id, 512 blocks
    const int b    = t >> 13;
    const int n    = t & (NP - 1);

    if (w == 0) {
        const float* xb = xyz + (size_t)b * 3 * NP;
        float x = xb[n], y = xb[NP + n], z = xb[2 * NP + n];
        float s = x * x + y * y + z * z;
        pts4[t] = make_float4(x, y, z, s);
        ptsS[t] = make_float4(-2.f * x, -2.f * y, -2.f * z, s);
    }

    const float* pb = points + (size_t)b * DIN * NP + n;
    float p[DIN];
#pragma unroll
    for (int c = 0; c < DIN; ++c) p[c] = pb[c * NP];

    uint4 outv;
    unsigned* ov = (unsigned*)&outv;
#pragma unroll
    for (int r = 0; r < 4; ++r) {
        int oe = w * 8 + 2 * r;
        float a0 = 0.f, a1 = 0.f;
#pragma unroll
        for (int c = 0; c < DIN; ++c) {
            a0 = fmaf(W0[oe * 35 + 3 + c], p[c], a0);
            a1 = fmaf(W0[(oe + 1) * 35 + 3 + c], p[c], a1);
        }
        ov[r] = bf16rn(a0) | (bf16rn(a1) << 16);
    }
    *(uint4*)(featb + (size_t)t * 16 + w * 4) = outv;
}

// ---------------------------------------------------------------------------
// Kernel 2: exact 16-NN. r13 structure, distances now via v_pk_fma_f32 over
// SoA-packed point pairs (12 pk_fma per 8-point unit vs 24 v_fma). The fma
// chain per point is unchanged -> t values bit-identical -> same threshold,
// candidates and output indices. launch_bounds min-waves=8 pins VGPR<=64 so
// occupancy stays at 2 blocks/CU (32 waves = HW max).
// ---------------------------------------------------------------------------
__global__ __launch_bounds__(1024, 8) void knn_kernel(const float4* __restrict__ pts4,
                                                      const float4* __restrict__ ptsS,
                                                      int* __restrict__ idxout)
{
    __shared__ unsigned skey[64 * 65];              // 16.6 KB class-min keys
    __shared__ float    sT[64];
    __shared__ int      scnt[64];
    __shared__ float    cand_t[64 * CSTR];          // 20.7 KB
    __shared__ int      cand_i[64 * CSTR];          // 20.7 KB

    const int tid  = threadIdx.x;
    const int w    = __builtin_amdgcn_readfirstlane(tid >> 6);
    const int lane = tid & 63;
    const int blk  = blockIdx.x;           // 512 blocks
    const int b    = blk >> 7;
    const int n0   = (blk & 127) << 6;
    const int bn0  = b * NP;
    const float4* P  = pts4 + bn0;         // raw (queries, fallback)
    const float4* S  = ptsS + bn0;         // pre-scaled (scan points)
    const float4* Pq = P + n0;             // this block's 64 queries

    for (int i = tid; i < 64 * 65; i += 1024) skey[i] = 0xFFFFFFFFu;
    if (tid < 64) scnt[tid] = 0;
    __syncthreads();

    // ---- load my 8 pre-scaled points, SoA-packed into f32x2 pairs ----
    const int base = w * SEG;
    f32x2 sx[4], sy[4], sz[4], sw2[4];
#pragma unroll
    for (int jp = 0; jp < 4; ++jp) {
        float4 a = S[base + (2 * jp) * 64 + lane];
        float4 c = S[base + (2 * jp + 1) * 64 + lane];
        sx[jp].x = a.x;  sx[jp].y = c.x;
        sy[jp].x = a.y;  sy[jp].y = c.y;
        sz[jp].x = a.z;  sz[jp].y = c.z;
        sw2[jp].x = a.w; sw2[jp].y = c.w;
    }

    // ---- pass 1: chunks of 8 queries via s_load; packed fma; min3-tree ----
#pragma unroll 1
    for (int qc = 0; qc < 8; ++qc) {
        float4 qv[8];
#pragma unroll
        for (int i = 0; i < 8; ++i) qv[i] = Pq[qc * 8 + i];   // uniform -> s_load
#pragma unroll
        for (int i = 0; i < 8; ++i) {
            f32x2 qx, qy, qz;
            qx.x = qv[i].x; qx.y = qv[i].x;    // uniform -> SGPR pair
            qy.x = qv[i].y; qy.y = qv[i].y;
            qz.x = qv[i].z; qz.y = qv[i].z;
            f32x2 t0 = pk_fma(sz[0], qz, sw2[0]);
            f32x2 t1 = pk_fma(sz[1], qz, sw2[1]);
            f32x2 t2 = pk_fma(sz[2], qz, sw2[2]);
            f32x2 t3 = pk_fma(sz[3], qz, sw2[3]);
            t0 = pk_fma(sy[0], qy, t0);  t1 = pk_fma(sy[1], qy, t1);
            t2 = pk_fma(sy[2], qy, t2);  t3 = pk_fma(sy[3], qy, t3);
            t0 = pk_fma(sx[0], qx, t0);  t1 = pk_fma(sx[1], qx, t1);
            t2 = pk_fma(sx[2], qx, t2);  t3 = pk_fma(sx[3], qx, t3);
            // same min tree as scalar version (fmin exactly associative)
            float a  = fminf(fminf(t0.x, t0.y), t1.x);   // v_min3
            float b2 = fminf(fminf(t1.y, t2.x), t2.y);   // v_min3
            float c2 = fminf(fminf(t3.x, t3.y), a);      // v_min3
            float mn = fminf(b2, c2);
            atomicMin(&skey[(qc * 8 + i) * 65 + lane], fkey(mn));
        }
    }
    __syncthreads();

    // ---- threshold: 16th smallest of the 64 class minima (thread = query) ----
    if (tid < 64) {
        unsigned t16[16];
#pragma unroll
        for (int i = 0; i < 16; ++i) t16[i] = 0xFFFFFFFFu;
        for (int c = 0; c < 64; ++c) {
            unsigned d = skey[tid * 65 + c];
            if (d < t16[15]) {
                t16[15] = d;
#pragma unroll
                for (int i = 15; i > 0; --i) {
                    unsigned a = t16[i - 1], cc = t16[i];
                    t16[i - 1] = umin_(a, cc);
                    t16[i]     = umax_(a, cc);
                }
            }
        }
        sT[tid] = funkey(t16[15]);
    }
    __syncthreads();

    // ---- pass 2: bit-identical recompute (packed), per-point t<=T append ----
#pragma unroll 1
    for (int qc = 0; qc < 8; ++qc) {
        float4 qv[8];
#pragma unroll
        for (int i = 0; i < 8; ++i) qv[i] = Pq[qc * 8 + i];   // uniform -> s_load
#pragma unroll
        for (int i = 0; i < 8; ++i) {
            const int q = qc * 8 + i;
            const float T = sT[q];
            f32x2 qx, qy, qz;
            qx.x = qv[i].x; qx.y = qv[i].x;
            qy.x = qv[i].y; qy.y = qv[i].y;
            qz.x = qv[i].z; qz.y = qv[i].z;
#pragma unroll
            for (int jp = 0; jp < 4; ++jp) {
                f32x2 t = pk_fma(sz[jp], qz, sw2[jp]);
                t = pk_fma(sy[jp], qy, t);
                t = pk_fma(sx[jp], qx, t);
                if (t.x <= T) {
                    int pos = atomicAdd(&scnt[q], 1);
                    if (pos < CAP) {
                        cand_t[q * CSTR + pos] = t.x;
                        cand_i[q * CSTR + pos] = base + (2 * jp) * 64 + lane;
                    }
                }
                if (t.y <= T) {
                    int pos = atomicAdd(&scnt[q], 1);
                    if (pos < CAP) {
                        cand_t[q * CSTR + pos] = t.y;
                        cand_i[q * CSTR + pos] = base + (2 * jp + 1) * 64 + lane;
                    }
                }
            }
        }
    }
    __syncthreads();

    // ---- exact selection among candidates (thread = query) ----
    if (tid < 64) {
        int cnt = scnt[tid];
        int* outp = idxout + ((bn0 + n0 + tid) << 4);
        float bd[16]; int bi[16];
#pragma unroll
        for (int i = 0; i < 16; ++i) { bd[i] = 3e38f; bi[i] = 0; }
        if (cnt <= CAP) {
            for (int pos = 0; pos < cnt; ++pos) {
                float d = cand_t[tid * CSTR + pos];
                int   j = cand_i[tid * CSTR + pos];
                if ((d < bd[15]) || (d == bd[15] && j < bi[15])) {
                    bd[15] = d; bi[15] = j;
#pragma unroll
                    for (int i = 15; i > 0; --i) {
                        bool sw = (bd[i] < bd[i - 1]) || (bd[i] == bd[i - 1] && bi[i] < bi[i - 1]);
                        float td = bd[i - 1]; int tj = bi[i - 1];
                        bd[i - 1] = sw ? bd[i] : td;  bi[i - 1] = sw ? bi[i] : tj;
                        bd[i]     = sw ? td : bd[i];  bi[i]     = sw ? tj : bi[i];
                    }
                }
            }
        } else {
            // overflow fallback (exact, never expected): identical fma form
            float4 q4 = Pq[tid];
            for (int j = 0; j < NP; ++j) {
                float4 s = S[j];
                float d = fmaf(q4.x, s.x, fmaf(q4.y, s.y, fmaf(q4.z, s.z, s.w)));
                if ((d < bd[15]) || (d == bd[15] && j < bi[15])) {
                    bd[15] = d; bi[15] = j;
#pragma unroll
                    for (int i = 15; i > 0; --i) {
                        bool sw = (bd[i] < bd[i - 1]) || (bd[i] == bd[i - 1] && bi[i] < bi[i - 1]);
                        float td = bd[i - 1]; int tj = bi[i - 1];
                        bd[i - 1] = sw ? bd[i] : td;  bi[i - 1] = sw ? bi[i] : tj;
                        bd[i]     = sw ? td : bd[i];  bi[i]     = sw ? tj : bi[i];
                    }
                }
            }
        }
#pragma unroll
        for (int i = 0; i < 16; ++i) outp[i] = bi[i];
    }
}

// ---------------------------------------------------------------------------
// Kernel 3: gather + conv0/1/2 + max over K. conv1/conv2 inner products now
// packed over the contiguous c axis: weight pairs (W[o][c],W[o][c+1]) are
// aligned float2 s_loads (uniform, SGPR pair operand), activations held as
// f32x2. 3072 scalar fma -> ~1600 pk_fma per thread.
// ---------------------------------------------------------------------------
__global__ __launch_bounds__(256, 4) void conv_kernel(
    const float4* __restrict__ pts4, const unsigned* __restrict__ featb,
    const int* __restrict__ idx,
    const float* __restrict__ W0, const float* __restrict__ W1, const float* __restrict__ W2,
    float* __restrict__ out)
{
    __shared__ float so[M2][17];
    const int tid = threadIdx.x;
    const int k   = tid & 15;
    const int nl  = tid >> 4;              // 0..15
    const int blk = blockIdx.x;            // 2048 blocks
    const int b   = blk >> 9;              // 512 blocks per batch
    const int n0  = (blk & 511) << 4;
    const int n   = n0 + nl;
    const int bn  = b * NP + n;
    const int j   = idx[(bn << 4) + k];
    const int bj  = b * NP + j;

    const float4 pc = pts4[bn];
    const float4 pj = pts4[bj];
    const float rx = pj.x - pc.x, ry = pj.y - pc.y, rz = pj.z - pc.z;

    const uint4* fj = (const uint4*)(featb + (size_t)bj * 16);

    f32x2 x0p[16];                         // packed (even,odd) conv0 outputs
#pragma unroll
    for (int g = 0; g < 4; ++g) {
        uint4 u = fj[g];
        const unsigned* uv = (const unsigned*)&u;
#pragma unroll
        for (int r = 0; r < 4; ++r) {
            int o = g * 8 + 2 * r;
            float fe  = __uint_as_float(uv[r] << 16);
            float fo_ = __uint_as_float(uv[r] & 0xffff0000u);
            x0p[o >> 1].x = lrelu(fmaf(W0[o * 35], rx, fmaf(W0[o * 35 + 1], ry, fmaf(W0[o * 35 + 2], rz, fe))));
            x0p[o >> 1].y = lrelu(fmaf(W0[(o + 1) * 35], rx, fmaf(W0[(o + 1) * 35 + 1], ry, fmaf(W0[(o + 1) * 35 + 2], rz, fo_))));
        }
    }

    f32x2 x1p[16];
#pragma unroll
    for (int op = 0; op < 16; ++op) {
        const f32x2* wa = (const f32x2*)(W1 + (2 * op) * 32);      // aligned, uniform
        const f32x2* wb = (const f32x2*)(W1 + (2 * op + 1) * 32);
        f32x2 acc0; acc0.x = 0.f; acc0.y = 0.f;
        f32x2 acc1; acc1.x = 0.f; acc1.y = 0.f;
#pragma unroll
        for (int i = 0; i < 16; ++i) {
            acc0 = pk_fma(x0p[i], wa[i], acc0);
            acc1 = pk_fma(x0p[i], wb[i], acc1);
        }
        x1p[op].x = lrelu(acc0.x + acc0.y);
        x1p[op].y = lrelu(acc1.x + acc1.y);
    }

#pragma unroll
    for (int o = 0; o < M2; ++o) {
        const f32x2* wp = (const f32x2*)(W2 + o * 32);
        f32x2 acc; acc.x = 0.f; acc.y = 0.f;
#pragma unroll
        for (int i = 0; i < 16; ++i) acc = pk_fma(x1p[i], wp[i], acc);
        float v = lrelu(acc.x + acc.y);
        // 16-lane max reduce via DPP (VALU-rate, no DS):
        v = fmax_dpp<0xB1>(v);    // quad_perm xor1
        v = fmax_dpp<0x4E>(v);    // quad_perm xor2
        v = fmax_dpp<0x141>(v);   // row_half_mirror: quad0<->1, quad2<->3
        v = fmax_dpp<0x140>(v);   // row_mirror: halves
        if (k == (o & 15)) so[o][nl] = v;
    }
    __syncthreads();
    {
        int o = tid >> 2;                 // 0..63
        int col = (tid & 3) << 2;         // 0,4,8,12
        float4 v = make_float4(so[o][col], so[o][col + 1], so[o][col + 2], so[o][col + 3]);
        *(float4*)(out + ((size_t)(b * M2 + o)) * NP + n0 + col) = v;
    }
}

// ---------------------------------------------------------------------------
extern "C" void kernel_launch(void* const* d_in, const int* in_sizes, int n_in,
                              void* d_out, int out_size, void* d_ws, size_t ws_size,
                              hipStream_t stream)
{
    const float* xyz    = (const float*)d_in[0];
    const float* points = (const float*)d_in[1];
    const float* W0     = (const float*)d_in[2];
    const float* W1     = (const float*)d_in[3];
    const float* W2     = (const float*)d_in[4];
    float* out = (float*)d_out;

    char* ws = (char*)d_ws;
    float4*   pts4  = (float4*)ws;                       // 512 KB
    float4*   ptsS  = (float4*)(ws + 0x080000);          // 512 KB (pre-scaled)
    unsigned* featb = (unsigned*)(ws + 0x100000);        // 2 MB
    int*      idx   = (int*)(ws + 0x300000);             // 2 MB

    prep_kernel<<<BB * NP / 64, 256,  0, stream>>>(xyz, points, W0, pts4, ptsS, featb);
    knn_kernel <<<BB * NP / 64, 1024, 0, stream>>>(pts4, ptsS, idx);
    conv_kernel<<<BB * NP / 16, 256,  0, stream>>>(pts4, featb, idx, W0, W1, W2, out);
}

// Round 2
// 194.906 us; speedup vs baseline: 1.1959x; 1.1249x over previous
//
#include <hip/hip_runtime.h>

#define NP   8192
#define BB   4
#define DIN  32
#define M0   32
#define M1   32
#define M2   64
#define CAP  80
#define CSTR 81            // candidate row stride (odd -> conflict-free)
#define KWV  16            // waves per knn block
#define SEG  (NP / KWV)    // 512 points per wave

typedef float f32x2 __attribute__((ext_vector_type(2)));
typedef float f32x4 __attribute__((ext_vector_type(4)));
typedef short bf16x8 __attribute__((ext_vector_type(8)));

__device__ __forceinline__ float lrelu(float x) { return fmaxf(x, 0.1f * x); }
__device__ __forceinline__ unsigned umin_(unsigned a, unsigned b) { return a < b ? a : b; }
__device__ __forceinline__ unsigned umax_(unsigned a, unsigned b) { return a > b ? a : b; }

// monotonic float->uint key (total order incl. negatives)
__device__ __forceinline__ unsigned fkey(float f) {
    unsigned b = __float_as_uint(f);
    return (b & 0x80000000u) ? ~b : (b | 0x80000000u);
}
__device__ __forceinline__ float funkey(unsigned k) {
    unsigned b = (k & 0x80000000u) ? (k & 0x7fffffffu) : ~k;
    return __uint_as_float(b);
}

// round-to-nearest-even f32 -> bf16 (as uint16 in low bits)
__device__ __forceinline__ unsigned bf16rn(float f) {
    unsigned u = __float_as_uint(f);
    unsigned r = (u >> 16) & 1u;
    return (u + 0x7fffu + r) >> 16;
}

// packed f32 FMA (knn): d = a*b + c per half; b wave-uniform -> SGPR pair.
__device__ __forceinline__ f32x2 pk_fma(f32x2 a, f32x2 b, f32x2 c) {
    f32x2 d;
    asm("v_pk_fma_f32 %0, %1, %2, %3" : "=v"(d) : "v"(a), "s"(b), "v"(c));
    return d;
}

// max with a DPP-permuted copy: full VALU rate, no DS pipe.
template<int CTRL>
__device__ __forceinline__ float fmax_dpp(float v) {
    int s = __builtin_amdgcn_update_dpp(0, __float_as_int(v), CTRL, 0xf, 0xf, true);
    return fmaxf(v, __int_as_float(s));
}

// hi/lo bf16 split of a float pair, packed as two u32 (lo16|hi16 each).
// hi = bit-truncation (exact residual via same-exponent subtract);
// lo = trunc-bf16(residual): x ~= hi+lo to ~2^-16 relative.
__device__ __forceinline__ void split_pack2(float f0, float f1, unsigned& hp, unsigned& lp) {
    unsigned u0 = __float_as_uint(f0), u1 = __float_as_uint(f1);
    unsigned h0 = u0 & 0xffff0000u, h1 = u1 & 0xffff0000u;
    hp = (u0 >> 16) | h1;
    float r0 = f0 - __uint_as_float(h0);
    float r1 = f1 - __uint_as_float(h1);
    lp = (__float_as_uint(r0) >> 16) | (__float_as_uint(r1) & 0xffff0000u);
}

// Build hi/lo bf16 A-fragments from 8 consecutive f32 weights.
__device__ __forceinline__ void wfrag(const float* wrow, bf16x8& h, bf16x8& lo) {
    float4 a = *(const float4*)(wrow);
    float4 b = *(const float4*)(wrow + 4);
    unsigned* hv = (unsigned*)&h;
    unsigned* lv = (unsigned*)&lo;
    split_pack2(a.x, a.y, hv[0], lv[0]);
    split_pack2(a.z, a.w, hv[1], lv[1]);
    split_pack2(b.x, b.y, hv[2], lv[2]);
    split_pack2(b.z, b.w, hv[3], lv[3]);
}

__device__ __forceinline__ f32x4 mfma16(bf16x8 a, bf16x8 b, f32x4 c) {
    return __builtin_amdgcn_mfma_f32_16x16x32_bf16(a, b, c, 0, 0, 0);
}

// ---------------------------------------------------------------------------
// Kernel 1: pack pts4 = (x,y,z,|p|^2), ptsS = (-2x,-2y,-2z,|p|^2) and
// feat = W0[:,3:] @ points stored as bf16 pairs. (unchanged)
// ---------------------------------------------------------------------------
__global__ __launch_bounds__(256) void prep_kernel(
    const float* __restrict__ xyz, const float* __restrict__ points,
    const float* __restrict__ W0, float4* __restrict__ pts4,
    float4* __restrict__ ptsS, unsigned* __restrict__ featb)
{
    const int tid  = threadIdx.x;
    const int w    = __builtin_amdgcn_readfirstlane(tid >> 6);  // 0..3
    const int lane = tid & 63;
    const int t    = blockIdx.x * 64 + lane;     // point id, 512 blocks
    const int b    = t >> 13;
    const int n    = t & (NP - 1);

    if (w == 0) {
        const float* xb = xyz + (size_t)b * 3 * NP;
        float x = xb[n], y = xb[NP + n], z = xb[2 * NP + n];
        float s = x * x + y * y + z * z;
        pts4[t] = make_float4(x, y, z, s);
        ptsS[t] = make_float4(-2.f * x, -2.f * y, -2.f * z, s);
    }

    const float* pb = points + (size_t)b * DIN * NP + n;
    float p[DIN];
#pragma unroll
    for (int c = 0; c < DIN; ++c) p[c] = pb[c * NP];

    uint4 outv;
    unsigned* ov = (unsigned*)&outv;
#pragma unroll
    for (int r = 0; r < 4; ++r) {
        int oe = w * 8 + 2 * r;
        float a0 = 0.f, a1 = 0.f;
#pragma unroll
        for (int c = 0; c < DIN; ++c) {
            a0 = fmaf(W0[oe * 35 + 3 + c], p[c], a0);
            a1 = fmaf(W0[(oe + 1) * 35 + 3 + c], p[c], a1);
        }
        ov[r] = bf16rn(a0) | (bf16rn(a1) << 16);
    }
    *(uint4*)(featb + (size_t)t * 16 + w * 4) = outv;
}

// ---------------------------------------------------------------------------
// Kernel 2: exact 16-NN (unchanged from round 1 — packed v_pk_fma distances).
// ---------------------------------------------------------------------------
__global__ __launch_bounds__(1024, 8) void knn_kernel(const float4* __restrict__ pts4,
                                                      const float4* __restrict__ ptsS,
                                                      int* __restrict__ idxout)
{
    __shared__ unsigned skey[64 * 65];              // 16.6 KB class-min keys
    __shared__ float    sT[64];
    __shared__ int      scnt[64];
    __shared__ float    cand_t[64 * CSTR];          // 20.7 KB
    __shared__ int      cand_i[64 * CSTR];          // 20.7 KB

    const int tid  = threadIdx.x;
    const int w    = __builtin_amdgcn_readfirstlane(tid >> 6);
    const int lane = tid & 63;
    const int blk  = blockIdx.x;           // 512 blocks
    const int b    = blk >> 7;
    const int n0   = (blk & 127) << 6;
    const int bn0  = b * NP;
    const float4* P  = pts4 + bn0;         // raw (queries, fallback)
    const float4* S  = ptsS + bn0;         // pre-scaled (scan points)
    const float4* Pq = P + n0;             // this block's 64 queries

    for (int i = tid; i < 64 * 65; i += 1024) skey[i] = 0xFFFFFFFFu;
    if (tid < 64) scnt[tid] = 0;
    __syncthreads();

    // ---- load my 8 pre-scaled points, SoA-packed into f32x2 pairs ----
    const int base = w * SEG;
    f32x2 sx[4], sy[4], sz[4], sw2[4];
#pragma unroll
    for (int jp = 0; jp < 4; ++jp) {
        float4 a = S[base + (2 * jp) * 64 + lane];
        float4 c = S[base + (2 * jp + 1) * 64 + lane];
        sx[jp].x = a.x;  sx[jp].y = c.x;
        sy[jp].x = a.y;  sy[jp].y = c.y;
        sz[jp].x = a.z;  sz[jp].y = c.z;
        sw2[jp].x = a.w; sw2[jp].y = c.w;
    }

    // ---- pass 1: chunks of 8 queries via s_load; packed fma; min3-tree ----
#pragma unroll 1
    for (int qc = 0; qc < 8; ++qc) {
        float4 qv[8];
#pragma unroll
        for (int i = 0; i < 8; ++i) qv[i] = Pq[qc * 8 + i];   // uniform -> s_load
#pragma unroll
        for (int i = 0; i < 8; ++i) {
            f32x2 qx, qy, qz;
            qx.x = qv[i].x; qx.y = qv[i].x;    // uniform -> SGPR pair
            qy.x = qv[i].y; qy.y = qv[i].y;
            qz.x = qv[i].z; qz.y = qv[i].z;
            f32x2 t0 = pk_fma(sz[0], qz, sw2[0]);
            f32x2 t1 = pk_fma(sz[1], qz, sw2[1]);
            f32x2 t2 = pk_fma(sz[2], qz, sw2[2]);
            f32x2 t3 = pk_fma(sz[3], qz, sw2[3]);
            t0 = pk_fma(sy[0], qy, t0);  t1 = pk_fma(sy[1], qy, t1);
            t2 = pk_fma(sy[2], qy, t2);  t3 = pk_fma(sy[3], qy, t3);
            t0 = pk_fma(sx[0], qx, t0);  t1 = pk_fma(sx[1], qx, t1);
            t2 = pk_fma(sx[2], qx, t2);  t3 = pk_fma(sx[3], qx, t3);
            // same min tree as scalar version (fmin exactly associative)
            float a  = fminf(fminf(t0.x, t0.y), t1.x);   // v_min3
            float b2 = fminf(fminf(t1.y, t2.x), t2.y);   // v_min3
            float c2 = fminf(fminf(t3.x, t3.y), a);      // v_min3
            float mn = fminf(b2, c2);
            atomicMin(&skey[(qc * 8 + i) * 65 + lane], fkey(mn));
        }
    }
    __syncthreads();

    // ---- threshold: 16th smallest of the 64 class minima (thread = query) ----
    if (tid < 64) {
        unsigned t16[16];
#pragma unroll
        for (int i = 0; i < 16; ++i) t16[i] = 0xFFFFFFFFu;
        for (int c = 0; c < 64; ++c) {
            unsigned d = skey[tid * 65 + c];
            if (d < t16[15]) {
                t16[15] = d;
#pragma unroll
                for (int i = 15; i > 0; --i) {
                    unsigned a = t16[i - 1], cc = t16[i];
                    t16[i - 1] = umin_(a, cc);
                    t16[i]     = umax_(a, cc);
                }
            }
        }
        sT[tid] = funkey(t16[15]);
    }
    __syncthreads();

    // ---- pass 2: bit-identical recompute (packed), per-point t<=T append ----
#pragma unroll 1
    for (int qc = 0; qc < 8; ++qc) {
        float4 qv[8];
#pragma unroll
        for (int i = 0; i < 8; ++i) qv[i] = Pq[qc * 8 + i];   // uniform -> s_load
#pragma unroll
        for (int i = 0; i < 8; ++i) {
            const int q = qc * 8 + i;
            const float T = sT[q];
            f32x2 qx, qy, qz;
            qx.x = qv[i].x; qx.y = qv[i].x;
            qy.x = qv[i].y; qy.y = qv[i].y;
            qz.x = qv[i].z; qz.y = qv[i].z;
#pragma unroll
            for (int jp = 0; jp < 4; ++jp) {
                f32x2 t = pk_fma(sz[jp], qz, sw2[jp]);
                t = pk_fma(sy[jp], qy, t);
                t = pk_fma(sx[jp], qx, t);
                if (t.x <= T) {
                    int pos = atomicAdd(&scnt[q], 1);
                    if (pos < CAP) {
                        cand_t[q * CSTR + pos] = t.x;
                        cand_i[q * CSTR + pos] = base + (2 * jp) * 64 + lane;
                    }
                }
                if (t.y <= T) {
                    int pos = atomicAdd(&scnt[q], 1);
                    if (pos < CAP) {
                        cand_t[q * CSTR + pos] = t.y;
                        cand_i[q * CSTR + pos] = base + (2 * jp + 1) * 64 + lane;
                    }
                }
            }
        }
    }
    __syncthreads();

    // ---- exact selection among candidates (thread = query) ----
    if (tid < 64) {
        int cnt = scnt[tid];
        int* outp = idxout + ((bn0 + n0 + tid) << 4);
        float bd[16]; int bi[16];
#pragma unroll
        for (int i = 0; i < 16; ++i) { bd[i] = 3e38f; bi[i] = 0; }
        if (cnt <= CAP) {
            for (int pos = 0; pos < cnt; ++pos) {
                float d = cand_t[tid * CSTR + pos];
                int   j = cand_i[tid * CSTR + pos];
                if ((d < bd[15]) || (d == bd[15] && j < bi[15])) {
                    bd[15] = d; bi[15] = j;
#pragma unroll
                    for (int i = 15; i > 0; --i) {
                        bool sw = (bd[i] < bd[i - 1]) || (bd[i] == bd[i - 1] && bi[i] < bi[i - 1]);
                        float td = bd[i - 1]; int tj = bi[i - 1];
                        bd[i - 1] = sw ? bd[i] : td;  bi[i - 1] = sw ? bi[i] : tj;
                        bd[i]     = sw ? td : bd[i];  bi[i]     = sw ? tj : bi[i];
                    }
                }
            }
        } else {
            // overflow fallback (exact, never expected): identical fma form
            float4 q4 = Pq[tid];
            for (int j = 0; j < NP; ++j) {
                float4 s = S[j];
                float d = fmaf(q4.x, s.x, fmaf(q4.y, s.y, fmaf(q4.z, s.z, s.w)));
                if ((d < bd[15]) || (d == bd[15] && j < bi[15])) {
                    bd[15] = d; bi[15] = j;
#pragma unroll
                    for (int i = 15; i > 0; --i) {
                        bool sw = (bd[i] < bd[i - 1]) || (bd[i] == bd[i - 1] && bi[i] < bi[i - 1]);
                        float td = bd[i - 1]; int tj = bi[i - 1];
                        bd[i - 1] = sw ? bd[i] : td;  bi[i - 1] = sw ? bi[i] : tj;
                        bd[i]     = sw ? td : bd[i];  bi[i]     = sw ? tj : bi[i];
                    }
                }
            }
        }
#pragma unroll
        for (int i = 0; i < 16; ++i) outp[i] = bi[i];
    }
}

// ---------------------------------------------------------------------------
// Kernel 3: gather + conv0 (f32 VALU) + conv1/conv2 via MFMA with hi/lo bf16
// split (x ~= hi+lo to 2^-16; D = Whi*Bhi + Whi*Blo + Wlo*Bhi -> f32-grade
// accuracy, no absmax shift). Weights live in 48 VGPRs of fragments loaded
// ONCE (kills the per-wave 12KB s_load weight streaming of the pk_fma
// version). Wave-private LDS staging: cols stride 40 bf16 (80B, 16B-aligned
// ds_read_b128 frags, 2-way bank alias = free). Block = 4 waves = 256 cols
// = 16n x 16k; wave w owns n-tiles t=0..3 (n_local = 4w+t), col = lane.
// k-max stays the DPP chain (C/D col index == k).
// ---------------------------------------------------------------------------
__global__ __launch_bounds__(256, 3) void conv_kernel(
    const float4* __restrict__ pts4, const unsigned* __restrict__ featb,
    const int* __restrict__ idx,
    const float* __restrict__ W0, const float* __restrict__ W1, const float* __restrict__ W2,
    float* __restrict__ out)
{
    __shared__ __align__(16) unsigned short sh_hi[4 * 2560];  // [wave][col 64][k 40]
    __shared__ __align__(16) unsigned short sh_lo[4 * 2560];
    __shared__ float so[M2][17];

    const int tid = threadIdx.x;
    const int w   = __builtin_amdgcn_readfirstlane(tid >> 6);  // wave 0..3
    const int l   = tid & 63;
    const int g   = l >> 4;                // k-group / n-within-wave for conv0
    const int q   = l & 15;                // spatial index (row of A / col of B)
    const int k   = tid & 15;              // neighbor index (== q)
    const int nl  = tid >> 4;              // 0..15 (== 4w+g)
    const int blk = blockIdx.x;            // 2048 blocks
    const int b   = blk >> 9;              // 512 blocks per batch
    const int n0  = (blk & 511) << 4;
    const int n   = n0 + nl;
    const int bn  = b * NP + n;
    const int j   = idx[(bn << 4) + k];
    const int bj  = b * NP + j;

    // ---- weight fragments (one-time; identical across lanesets, cached) ----
    bf16x8 w1h[2], w1l[2], w2h[4], w2l[4];
#pragma unroll
    for (int r = 0; r < 2; ++r) wfrag(W1 + (16 * r + q) * 32 + g * 8, w1h[r], w1l[r]);
#pragma unroll
    for (int rr = 0; rr < 4; ++rr) wfrag(W2 + (16 * rr + q) * 32 + g * 8, w2h[rr], w2l[rr]);

    // ---- gather + conv0 (f32, per-column) ----
    const float4 pc = pts4[bn];
    const float4 pj = pts4[bj];
    const float rx = pj.x - pc.x, ry = pj.y - pc.y, rz = pj.z - pc.z;

    const uint4* fj = (const uint4*)(featb + (size_t)bj * 16);

    float x0[M0];
#pragma unroll
    for (int gg = 0; gg < 4; ++gg) {
        uint4 u = fj[gg];
        const unsigned* uv = (const unsigned*)&u;
#pragma unroll
        for (int r = 0; r < 4; ++r) {
            int o = gg * 8 + 2 * r;
            float fe  = __uint_as_float(uv[r] << 16);
            float fo_ = __uint_as_float(uv[r] & 0xffff0000u);
            x0[o]     = lrelu(fmaf(W0[o * 35], rx, fmaf(W0[o * 35 + 1], ry, fmaf(W0[o * 35 + 2], rz, fe))));
            x0[o + 1] = lrelu(fmaf(W0[(o + 1) * 35], rx, fmaf(W0[(o + 1) * 35 + 1], ry, fmaf(W0[(o + 1) * 35 + 2], rz, fo_))));
        }
    }

    // ---- stage x0 into wave-private LDS as hi/lo bf16, col = lane ----
    unsigned short* hb = sh_hi + w * 2560 + l * 40;
    unsigned short* lb = sh_lo + w * 2560 + l * 40;
#pragma unroll
    for (int ch = 0; ch < 4; ++ch) {
        uint4 hv, lv;
        unsigned* hp = (unsigned*)&hv;
        unsigned* lp = (unsigned*)&lv;
#pragma unroll
        for (int p = 0; p < 4; ++p)
            split_pack2(x0[ch * 8 + 2 * p], x0[ch * 8 + 2 * p + 1], hp[p], lp[p]);
        *(uint4*)(hb + ch * 8) = hv;
        *(uint4*)(lb + ch * 8) = lv;
    }

    // ---- conv1: B-frags from LDS, 3-MFMA split per 16x16 tile ----
    const unsigned short* rbh = sh_hi + w * 2560;
    const unsigned short* rbl = sh_lo + w * 2560;
    bf16x8 b1h[4], b1l[4];
#pragma unroll
    for (int t = 0; t < 4; ++t) {
        b1h[t] = *(const bf16x8*)(rbh + (16 * t + q) * 40 + g * 8);
        b1l[t] = *(const bf16x8*)(rbl + (16 * t + q) * 40 + g * 8);
    }
    const f32x4 zz = {0.f, 0.f, 0.f, 0.f};
    f32x4 acc1[2][4];
#pragma unroll
    for (int r = 0; r < 2; ++r)
#pragma unroll
        for (int t = 0; t < 4; ++t) {
            f32x4 a = mfma16(w1l[r], b1h[t], zz);
            a = mfma16(w1h[r], b1l[t], a);
            acc1[r][t] = mfma16(w1h[r], b1h[t], a);
        }

    // ---- lrelu + write x1 back (same-wave DS ordering, no barrier) ----
#pragma unroll
    for (int r = 0; r < 2; ++r)
#pragma unroll
        for (int t = 0; t < 4; ++t) {
            float v0 = lrelu(acc1[r][t][0]);
            float v1 = lrelu(acc1[r][t][1]);
            float v2 = lrelu(acc1[r][t][2]);
            float v3 = lrelu(acc1[r][t][3]);
            uint2 hv, lv;
            split_pack2(v0, v1, hv.x, lv.x);
            split_pack2(v2, v3, hv.y, lv.y);
            int off = (16 * t + q) * 40 + 16 * r + 4 * g;   // rows 16r+4g..+3
            *(uint2*)(sh_hi + w * 2560 + off) = hv;
            *(uint2*)(sh_lo + w * 2560 + off) = lv;
        }

    // ---- conv2: B-frags of x1, two rr-halves to bound VGPR pressure ----
    bf16x8 b2h[4], b2l[4];
#pragma unroll
    for (int t = 0; t < 4; ++t) {
        b2h[t] = *(const bf16x8*)(rbh + (16 * t + q) * 40 + g * 8);
        b2l[t] = *(const bf16x8*)(rbl + (16 * t + q) * 40 + g * 8);
    }
#pragma unroll
    for (int h = 0; h < 2; ++h) {
#pragma unroll
        for (int r2 = 0; r2 < 2; ++r2) {
            const int rr = 2 * h + r2;
#pragma unroll
            for (int t = 0; t < 4; ++t) {
                f32x4 a = mfma16(w2l[rr], b2h[t], zz);
                a = mfma16(w2h[rr], b2l[t], a);
                a = mfma16(w2h[rr], b2h[t], a);
                // lrelu + k-max over cols (col index == k) via DPP
#pragma unroll
                for (int reg = 0; reg < 4; ++reg) {
                    float v = lrelu(a[reg]);
                    v = fmax_dpp<0xB1>(v);    // quad_perm xor1
                    v = fmax_dpp<0x4E>(v);    // quad_perm xor2
                    v = fmax_dpp<0x141>(v);   // row_half_mirror
                    v = fmax_dpp<0x140>(v);   // row_mirror: full 16-lane max
                    if (q == reg) so[16 * rr + 4 * g + reg][w * 4 + t] = v;
                }
            }
        }
    }
    __syncthreads();
    {
        int o = tid >> 2;                 // 0..63
        int col = (tid & 3) << 2;         // 0,4,8,12
        float4 v = make_float4(so[o][col], so[o][col + 1], so[o][col + 2], so[o][col + 3]);
        *(float4*)(out + ((size_t)(b * M2 + o)) * NP + n0 + col) = v;
    }
}

// ---------------------------------------------------------------------------
extern "C" void kernel_launch(void* const* d_in, const int* in_sizes, int n_in,
                              void* d_out, int out_size, void* d_ws, size_t ws_size,
                              hipStream_t stream)
{
    const float* xyz    = (const float*)d_in[0];
    const float* points = (const float*)d_in[1];
    const float* W0     = (const float*)d_in[2];
    const float* W1     = (const float*)d_in[3];
    const float* W2     = (const float*)d_in[4];
    float* out = (float*)d_out;

    char* ws = (char*)d_ws;
    float4*   pts4  = (float4*)ws;                       // 512 KB
    float4*   ptsS  = (float4*)(ws + 0x080000);          // 512 KB (pre-scaled)
    unsigned* featb = (unsigned*)(ws + 0x100000);        // 2 MB
    int*      idx   = (int*)(ws + 0x300000);             // 2 MB

    prep_kernel<<<BB * NP / 64, 256,  0, stream>>>(xyz, points, W0, pts4, ptsS, featb);
    knn_kernel <<<BB * NP / 64, 1024, 0, stream>>>(pts4, ptsS, idx);
    conv_kernel<<<BB * NP / 16, 256,  0, stream>>>(pts4, featb, idx, W0, W1, W2, out);
}